// Round 6
// baseline (244.191 us; speedup 1.0000x reference)
//
#include <hip/hip_runtime.h>

#define LEAKY(x) ((x) > 0.0f ? (x) : 0.01f * (x))

typedef __attribute__((ext_vector_type(8))) short bf16x8;      // MFMA A/B frag
typedef __attribute__((ext_vector_type(4))) float f32x4;       // MFMA C/D frag
typedef __attribute__((ext_vector_type(8))) unsigned short u16x8;
typedef __attribute__((ext_vector_type(4))) unsigned short u16x4;

__device__ __forceinline__ unsigned short f2bf(float f) {
    unsigned int u = __float_as_uint(f);
    unsigned int r = (u + 0x7fffu + ((u >> 16) & 1u)) >> 16;   // RNE
    return (unsigned short)r;
}
__device__ __forceinline__ float bf2f(unsigned short u) {
    return __uint_as_float(((unsigned int)u) << 16);
}

// ---------------- small builds ----------------

__global__ void k_dmax(const float* __restrict__ deadline, float* __restrict__ dmax) {
    __shared__ float red[256];
    int t = threadIdx.x;
    float m = -1e30f;
    for (int i = t; i < 16384; i += 256) m = fmaxf(m, deadline[i]);
    red[t] = m; __syncthreads();
    for (int s = 128; s > 0; s >>= 1) {
        if (t < s) red[t] = fmaxf(red[t], red[t + s]);
        __syncthreads();
    }
    if (t == 0) *dmax = red[0];
}

// rowsum + per-block max of r=1/dist; R not materialized
__global__ __launch_bounds__(256) void k_rowstats(const float* __restrict__ loc,
                                                  const float* __restrict__ deadline,
                                                  const float* __restrict__ dmaxv,
                                                  float* __restrict__ rowsum, float* __restrict__ pmax) {
    int blk = blockIdx.x;                       // 0..4095
    int wave = threadIdx.x >> 6, lane = threadIdx.x & 63;
    int bi = blk * 4 + wave;                    // b*512 + i
    int b = bi >> 9, i = bi & 511;
    float invd = 1.0f / (*dmaxv);
    const float* lb = loc + b * 1024;
    const float* db = deadline + b * 512;
    float xi = lb[i * 2], yi = lb[i * 2 + 1], zi = db[i] * invd;
    float lsum = 0.f, lmax = 0.f;
    for (int j = lane; j < 512; j += 64) {
        float d0 = xi - lb[j * 2], d1 = yi - lb[j * 2 + 1], d2 = zi - db[j] * invd;
        float dd = d0 * d0 + d1 * d1 + d2 * d2;
        float r = (j == i) ? 0.f : rsqrtf(dd);
        lsum += r; lmax = fmaxf(lmax, r);
    }
    for (int off = 32; off > 0; off >>= 1) {
        lsum += __shfl_down(lsum, off);
        lmax = fmaxf(lmax, __shfl_down(lmax, off));
    }
    __shared__ float smax[4];
    if (lane == 0) { rowsum[bi] = lsum; smax[wave] = lmax; }
    __syncthreads();
    if (threadIdx.x == 0) pmax[blk] = fmaxf(fmaxf(smax[0], smax[1]), fmaxf(smax[2], smax[3]));
}

__global__ void k_amax(const float* __restrict__ pmax, float* __restrict__ amaxf) {
    __shared__ float red[256];
    int t = threadIdx.x;
    float m = 0.f;
    for (int i = t; i < 4096; i += 256) m = fmaxf(m, pmax[i]);
    red[t] = m; __syncthreads();
    for (int s = 128; s > 0; s >>= 1) {
        if (t < s) red[t] = fmaxf(red[t], red[t + s]);
        __syncthreads();
    }
    if (t == 0) *amaxf = red[0];
}

// L bf16 (symmetric), recomputing r on the fly
__global__ void k_buildL(const float* __restrict__ loc, const float* __restrict__ deadline,
                         const float* __restrict__ dmaxv, const float* __restrict__ rowsum,
                         const float* __restrict__ amaxf, unsigned short* __restrict__ Lb) {
    int id = blockIdx.x * 256 + threadIdx.x;     // 2,097,152 threads * 4 elems
    float inv = 1.0f / (*amaxf);
    float invd = 1.0f / (*dmaxv);
    size_t e = (size_t)id * 4;
    size_t bi = e >> 9;
    int b = (int)(bi >> 9);
    int i = (int)(bi & 511);
    int j0 = (int)(e & 511);
    const float* lb = loc + b * 1024;
    const float* db = deadline + b * 512;
    float xi = lb[i * 2], yi = lb[i * 2 + 1], zi = db[i] * invd;
    float4 l01 = *(const float4*)(lb + j0 * 2);
    float4 l23 = *(const float4*)(lb + j0 * 2 + 4);
    float4 dj = *(const float4*)(db + j0);
    float diag = rowsum[bi] * inv - 1.0f;
    float jx[4] = {l01.x, l01.z, l23.x, l23.z};
    float jy[4] = {l01.y, l01.w, l23.y, l23.w};
    float jz[4] = {dj.x * invd, dj.y * invd, dj.z * invd, dj.w * invd};
    u16x4 o;
#pragma unroll
    for (int j = 0; j < 4; j++) {
        float d0 = xi - jx[j], d1 = yi - jy[j], d2 = zi - jz[j];
        float dd = d0 * d0 + d1 * d1 + d2 * d2;
        float v = (i == j0 + j) ? diag : -rsqrtf(dd) * inv;
        o[j] = f2bf(v);
    }
    *(u16x4*)(Lb + e) = o;
}

// F0 powers, bf16 row-major [16384][384] x3, 4 cols per thread
__global__ void k_F0pow(const float* __restrict__ loc, const float* __restrict__ deadline,
                        const float* __restrict__ dmaxv,
                        const float* __restrict__ Wi, const float* __restrict__ bi_,
                        unsigned short* __restrict__ P1, unsigned short* __restrict__ P2,
                        unsigned short* __restrict__ P3) {
    int id = blockIdx.x * 256 + threadIdx.x;     // 1,572,864
    int row = id / 96, c4 = (id % 96) * 4;
    float x0 = loc[row * 2], x1 = loc[row * 2 + 1], x2 = deadline[row] / (*dmaxv);
    float4 w0 = *(const float4*)(Wi + c4);
    float4 w1 = *(const float4*)(Wi + 384 + c4);
    float4 w2 = *(const float4*)(Wi + 768 + c4);
    float4 bb = *(const float4*)(bi_ + c4);
    float f[4] = {x0 * w0.x + x1 * w1.x + x2 * w2.x + bb.x,
                  x0 * w0.y + x1 * w1.y + x2 * w2.y + bb.y,
                  x0 * w0.z + x1 * w1.z + x2 * w2.z + bb.z,
                  x0 * w0.w + x1 * w1.w + x2 * w2.w + bb.w};
    u16x4 o1, o2, o3;
#pragma unroll
    for (int j = 0; j < 4; j++) {
        o1[j] = f2bf(f[j]); o2[j] = f2bf(f[j] * f[j]); o3[j] = f2bf(f[j] * f[j] * f[j]);
    }
    size_t e = (size_t)row * 384 + c4;
    *(u16x4*)(P1 + e) = o1; *(u16x4*)(P2 + e) = o2; *(u16x4*)(P3 + e) = o3;
}

// WgT[combo][n][k] = Wg{kp}[(part*384+k)*128 + n]
__global__ void k_prepW(const float* __restrict__ Wg1, const float* __restrict__ Wg2,
                        const float* __restrict__ Wg3, unsigned short* __restrict__ WgT) {
    int id = blockIdx.x * 256 + threadIdx.x;     // 442368 exact
    int combo = id / 49152, rem = id % 49152;
    int n = rem / 384, k = rem % 384;
    int kp = combo / 3, part = combo % 3;
    const float* W = (kp == 0) ? Wg1 : (kp == 1 ? Wg2 : Wg3);
    WgT[id] = f2bf(W[(part * 384 + k) * 128 + n]);
}

// ---------------- pipelined MFMA cores ----------------
// Depth-2 register prefetch (ping-pong stages) + double-buffered LDS, ONE barrier/iter.
// LDS rows of 64 u16 = 8 chunks of 16B; chunk XOR-swizzled by (row&7).
// 128x64 tile: 4 waves 2x2, wave tile 64x32 (4x2 frags), 16 MFMA/wave/iter.

__device__ __forceinline__ void pipe128x64(
    const unsigned short* __restrict__ A0, int As0, const unsigned short* __restrict__ B0, int Bs0, int it0,
    const unsigned short* __restrict__ A1, int As1, const unsigned short* __restrict__ B1, int Bs1, int it1,
    unsigned short* AsL, unsigned short* BsL,   // 16384 / 8192 u16 (double-buffered)
    f32x4 (&acc)[4][2], int t)
{
    const int lane = t & 63, wave = t >> 6;
    const int wm = wave >> 1, wn = wave & 1;
    const int quad = lane >> 4, l16 = lane & 15;
    const int ra = t >> 1, ca = (t & 1) * 4;        // A: 128 rows, 4 chunks/thread
    const int rb = t >> 2, cb = (t & 3) * 2;        // B: 64 rows, 2 chunks/thread
    const unsigned short* Ar0 = A0 + (size_t)ra * As0;
    const unsigned short* Ar1 = A1 ? (A1 + (size_t)ra * As1) : Ar0;
    const unsigned short* Br0 = B0 + (size_t)rb * Bs0;
    const unsigned short* Br1 = B1 ? (B1 + (size_t)rb * Bs1) : Br0;
    const int total = it0 + it1;                     // even in all call sites

    u16x8 paA[4], pbA[2], paB[4], pbB[2];

    auto loadStage = [&](int idx, u16x8 (&pa)[4], u16x8 (&pb)[2]) {
        int sg = (idx >= it0);
        int k0 = (sg ? idx - it0 : idx) * 64;
        const unsigned short* Ar = sg ? Ar1 : Ar0;
        const unsigned short* Br = sg ? Br1 : Br0;
#pragma unroll
        for (int j = 0; j < 4; j++) pa[j] = *(const u16x8*)(Ar + k0 + (ca + j) * 8);
#pragma unroll
        for (int j = 0; j < 2; j++) pb[j] = *(const u16x8*)(Br + k0 + (cb + j) * 8);
    };
    auto writeStage = [&](int bf_, u16x8 (&pa)[4], u16x8 (&pb)[2]) {
#pragma unroll
        for (int j = 0; j < 4; j++)
            *(u16x8*)(AsL + bf_ * 8192 + ra * 64 + (((ca + j) ^ (ra & 7)) * 8)) = pa[j];
#pragma unroll
        for (int j = 0; j < 2; j++)
            *(u16x8*)(BsL + bf_ * 4096 + rb * 64 + (((cb + j) ^ (rb & 7)) * 8)) = pb[j];
    };
    auto mfmaStep = [&](int bf_) {
#pragma unroll
        for (int h = 0; h < 2; h++) {
            bf16x8 af[4], bfr[2];
            int phys = ((h * 4 + quad) ^ (l16 & 7)) * 8;
#pragma unroll
            for (int i = 0; i < 4; i++)
                af[i] = *(const bf16x8*)(AsL + bf_ * 8192 + (wm * 64 + i * 16 + l16) * 64 + phys);
#pragma unroll
            for (int n = 0; n < 2; n++)
                bfr[n] = *(const bf16x8*)(BsL + bf_ * 4096 + (wn * 32 + n * 16 + l16) * 64 + phys);
#pragma unroll
            for (int i = 0; i < 4; i++)
#pragma unroll
                for (int n = 0; n < 2; n++)
                    acc[i][n] = __builtin_amdgcn_mfma_f32_16x16x32_bf16(af[i], bfr[n], acc[i][n], 0, 0, 0);
        }
    };

    loadStage(0, paA, pbA);
    loadStage(1, paB, pbB);

    int buf = 0;
    for (int s = 0; s < total; s += 2) {
        writeStage(buf, paA, pbA);
        __syncthreads();
        if (s + 2 < total) loadStage(s + 2, paA, pbA);
        mfmaStep(buf);
        buf ^= 1;

        writeStage(buf, paB, pbB);
        __syncthreads();
        if (s + 3 < total) loadStage(s + 3, paB, pbB);
        mfmaStep(buf);
        buf ^= 1;
    }
}

// 64x64 tile: wave tile 32x32 (2x2 frags), 8 MFMA/wave/iter, depth-2 prefetch
__device__ __forceinline__ void pipe64x64(
    const unsigned short* __restrict__ A0, int As0, const unsigned short* __restrict__ B0, int Bs0, int it0,
    unsigned short* AsL, unsigned short* BsL,   // 8192 / 8192 u16
    f32x4 (&acc)[2][2], int t)
{
    const int lane = t & 63, wave = t >> 6;
    const int wm = wave >> 1, wn = wave & 1;
    const int quad = lane >> 4, l16 = lane & 15;
    const int rb = t >> 2, cb = (t & 3) * 2;
    const unsigned short* Ar0 = A0 + (size_t)rb * As0;
    const unsigned short* Br0 = B0 + (size_t)rb * Bs0;

    u16x8 paA[2], pbA[2], paB[2], pbB[2];
    auto loadStage = [&](int idx, u16x8 (&pa)[2], u16x8 (&pb)[2]) {
        int k0 = idx * 64;
#pragma unroll
        for (int j = 0; j < 2; j++) { pa[j] = *(const u16x8*)(Ar0 + k0 + (cb + j) * 8);
                                      pb[j] = *(const u16x8*)(Br0 + k0 + (cb + j) * 8); }
    };
    auto writeStage = [&](int bf_, u16x8 (&pa)[2], u16x8 (&pb)[2]) {
#pragma unroll
        for (int j = 0; j < 2; j++) {
            int phys = ((cb + j) ^ (rb & 7)) * 8;
            *(u16x8*)(AsL + bf_ * 4096 + rb * 64 + phys) = pa[j];
            *(u16x8*)(BsL + bf_ * 4096 + rb * 64 + phys) = pb[j];
        }
    };
    auto mfmaStep = [&](int bf_) {
#pragma unroll
        for (int h = 0; h < 2; h++) {
            bf16x8 af[2], bfr[2];
            int phys = ((h * 4 + quad) ^ (l16 & 7)) * 8;
#pragma unroll
            for (int i = 0; i < 2; i++)
                af[i] = *(const bf16x8*)(AsL + bf_ * 4096 + (wm * 32 + i * 16 + l16) * 64 + phys);
#pragma unroll
            for (int n = 0; n < 2; n++)
                bfr[n] = *(const bf16x8*)(BsL + bf_ * 4096 + (wn * 32 + n * 16 + l16) * 64 + phys);
#pragma unroll
            for (int i = 0; i < 2; i++)
#pragma unroll
                for (int n = 0; n < 2; n++)
                    acc[i][n] = __builtin_amdgcn_mfma_f32_16x16x32_bf16(af[i], bfr[n], acc[i][n], 0, 0, 0);
        }
    };

    loadStage(0, paA, pbA);
    loadStage(1, paB, pbB);
    int buf = 0;
    for (int s = 0; s < it0; s += 2) {
        writeStage(buf, paA, pbA);
        __syncthreads();
        if (s + 2 < it0) loadStage(s + 2, paA, pbA);
        mfmaStep(buf);
        buf ^= 1;
        writeStage(buf, paB, pbB);
        __syncthreads();
        if (s + 3 < it0) loadStage(s + 3, paB, pbB);
        mfmaStep(buf);
        buf ^= 1;
    }
}

// Y2^T ; grid 768, id = b + 32*(kp + 3*nb)  (batch->XCD pinned, kp fastest)
__global__ __launch_bounds__(256) void k_ygemmT(
    const unsigned short* __restrict__ WgT,
    const unsigned short* __restrict__ P1, const unsigned short* __restrict__ P2,
    const unsigned short* __restrict__ P3, unsigned short* __restrict__ Y2T)
{
    __shared__ unsigned short AsL[16384], BsL[8192];
    const int t = threadIdx.x;
    const int id = blockIdx.x;
    const int b = id & 31, tt = id >> 5;
    const int kp = tt % 3, nb = tt / 3;
    const unsigned short* P = (kp == 0) ? P1 : (kp == 1 ? P2 : P3);
    f32x4 acc[4][2];
#pragma unroll
    for (int i = 0; i < 4; i++)
#pragma unroll
        for (int n = 0; n < 2; n++) acc[i][n] = (f32x4){0.f, 0.f, 0.f, 0.f};
    pipe128x64(WgT + (size_t)(kp * 3 + 2) * 49152, 384,
               P + ((size_t)b * 512 + nb * 64) * 384, 384, 6,
               nullptr, 0, nullptr, 0, 0, AsL, BsL, acc, t);

    const int wave = t >> 6, lane = t & 63;
    const int wm = wave >> 1, wn = wave & 1;
    const int quad = lane >> 4, l16 = lane & 15;
#pragma unroll
    for (int i = 0; i < 4; i++)
#pragma unroll
        for (int n = 0; n < 2; n++) {
            int g = kp * 128 + wm * 64 + i * 16 + quad * 4;
            int node = nb * 64 + wn * 32 + n * 16 + l16;
#pragma unroll
            for (int r = 0; r < 4; r++)
                Y2T[((size_t)b * 384 + g + r) * 512 + node] = f2bf(acc[i][n][r]);
        }
}

// Z^T = Y2T·L + WgT(part1)·P ; grid 768, id = b + 32*(kp + 3*nb)
__global__ __launch_bounds__(256) void k_lg1T(
    const unsigned short* __restrict__ Lb, const unsigned short* __restrict__ Y2T,
    const unsigned short* __restrict__ WgT,
    const unsigned short* __restrict__ P1, const unsigned short* __restrict__ P2,
    const unsigned short* __restrict__ P3, unsigned short* __restrict__ ZT)
{
    __shared__ unsigned short AsL[16384], BsL[8192];
    const int t = threadIdx.x;
    const int id = blockIdx.x;
    const int b = id & 31, tt = id >> 5;
    const int kp = tt % 3, nb = tt / 3;
    const unsigned short* P = (kp == 0) ? P1 : (kp == 1 ? P2 : P3);
    f32x4 acc[4][2];
#pragma unroll
    for (int i = 0; i < 4; i++)
#pragma unroll
        for (int n = 0; n < 2; n++) acc[i][n] = (f32x4){0.f, 0.f, 0.f, 0.f};
    pipe128x64(Y2T + (size_t)b * 196608 + (size_t)kp * 128 * 512, 512,
               Lb + (size_t)b * 262144 + (size_t)nb * 64 * 512, 512, 8,
               WgT + (size_t)(kp * 3 + 1) * 49152, 384,
               P + ((size_t)b * 512 + nb * 64) * 384, 384, 6, AsL, BsL, acc, t);

    const int wave = t >> 6, lane = t & 63;
    const int wm = wave >> 1, wn = wave & 1;
    const int quad = lane >> 4, l16 = lane & 15;
#pragma unroll
    for (int i = 0; i < 4; i++)
#pragma unroll
        for (int n = 0; n < 2; n++) {
            int g = kp * 128 + wm * 64 + i * 16 + quad * 4;
            int node = nb * 64 + wn * 32 + n * 16 + l16;
#pragma unroll
            for (int r = 0; r < 4; r++)
                ZT[((size_t)b * 384 + g + r) * 512 + node] = f2bf(acc[i][n][r]);
        }
}

// F1 = leaky(L·ZT + P·WgT(part0) + bias) + F0 ; fused BN sums
// grid 768, id = b + 32*(gt + 6*mb)  (gt fastest)
__global__ __launch_bounds__(256) void k_lg2(
    const unsigned short* __restrict__ Lb, const unsigned short* __restrict__ ZT,
    const unsigned short* __restrict__ WgT,
    const unsigned short* __restrict__ P1, const unsigned short* __restrict__ P2,
    const unsigned short* __restrict__ P3,
    const float* __restrict__ bg1, const float* __restrict__ bg2, const float* __restrict__ bg3,
    unsigned short* __restrict__ F1b, float* __restrict__ bn1, float* __restrict__ bn2)
{
    __shared__ unsigned short AsL[16384], BsL[8192];
    __shared__ float bnS[64], bnQ[64];
    const int t = threadIdx.x;
    const int id = blockIdx.x;
    const int b = id & 31, tt = id >> 5;
    const int gt = tt % 6, mb = tt / 6;          // mb: node tile(128), gt: gcol tile(64)
    const int kp = gt >> 1;
    if (t < 64) { bnS[t] = 0.f; bnQ[t] = 0.f; }
    const unsigned short* P = (kp == 0) ? P1 : (kp == 1 ? P2 : P3);
    f32x4 acc[4][2];
#pragma unroll
    for (int i = 0; i < 4; i++)
#pragma unroll
        for (int n = 0; n < 2; n++) acc[i][n] = (f32x4){0.f, 0.f, 0.f, 0.f};
    pipe128x64(Lb + (size_t)b * 262144 + (size_t)mb * 128 * 512, 512,
               ZT + (size_t)b * 196608 + (size_t)gt * 64 * 512, 512, 8,
               P + ((size_t)b * 512 + mb * 128) * 384, 384,
               WgT + (size_t)(kp * 3) * 49152 + (size_t)(gt & 1) * 64 * 384, 384, 6,
               AsL, BsL, acc, t);

    const int wave = t >> 6, lane = t & 63;
    const int wm = wave >> 1, wn = wave & 1;
    const int quad = lane >> 4, l16 = lane & 15;
    const float* bg = (kp == 0) ? bg1 : (kp == 1 ? bg2 : bg3);
    float ls1[2], ls2[2];
#pragma unroll
    for (int n = 0; n < 2; n++) { ls1[n] = 0.f; ls2[n] = 0.f; }
#pragma unroll
    for (int i = 0; i < 4; i++) {
        int rowl = mb * 128 + wm * 64 + i * 16 + quad * 4;
        size_t rowg = (size_t)b * 512 + rowl;
#pragma unroll
        for (int n = 0; n < 2; n++) {
            int nloc = wn * 32 + n * 16 + l16;
            int g = gt * 64 + nloc;
            float bias = bg[(gt & 1) * 64 + nloc];
#pragma unroll
            for (int r = 0; r < 4; r++) {
                size_t idx = (rowg + r) * 384 + g;
                float c = acc[i][n][r] + bias;
                float v = LEAKY(c) + bf2f(P1[idx]);   // residual +F0
                F1b[idx] = f2bf(v);
                ls1[n] += v; ls2[n] += v * v;
            }
        }
    }
#pragma unroll
    for (int n = 0; n < 2; n++) {
        int nloc = wn * 32 + n * 16 + l16;
        atomicAdd(&bnS[nloc], ls1[n]);
        atomicAdd(&bnQ[nloc], ls2[n]);
    }
    __syncthreads();
    if (t < 64) {
        atomicAdd(&bn1[gt * 64 + t], bnS[t]);
        atomicAdd(&bn2[gt * 64 + t], bnQ[t]);
    }
}

// BN finish + effective bias
__global__ __launch_bounds__(384) void k_bnfin_beff(
    const float* __restrict__ bn1, const float* __restrict__ bn2,
    const float* __restrict__ gamma, const float* __restrict__ beta,
    const float* __restrict__ WF, const float* __restrict__ bF,
    float* __restrict__ sS, float* __restrict__ beffv)
{
    __shared__ float ttL[384];
    int c = threadIdx.x;
    float mu = bn1[c] * (1.f / 16384.f);
    float var = bn2[c] * (1.f / 16384.f) - mu * mu;
    float sc = gamma[c] / sqrtf(var + 1e-5f);
    sS[c] = sc;
    ttL[c] = beta[c] - mu * sc;
    __syncthreads();
    if (c < 128) {
        float a = bF[c];
        for (int k = 0; k < 384; k++) a += ttL[k] * WF[k * 128 + c];
        beffv[c] = a;
    }
}

// WFsT[n][k] = W_F[k][n] * sS[k]
__global__ void k_fold(const float* __restrict__ WF, const float* __restrict__ sS,
                       unsigned short* __restrict__ WFsT) {
    int id = blockIdx.x * 256 + threadIdx.x;   // 49152
    int n = id / 384, k = id % 384;
    WFsT[id] = f2bf(WF[k * 128 + n] * sS[k]);
}

// out rows 1..512 = leaky(F1b @ WFsT + beff); fused column-sum partials
__global__ __launch_bounds__(256) void k_fgemm(
    const unsigned short* __restrict__ F1b, const unsigned short* __restrict__ WFsT,
    const float* __restrict__ beffv, float* __restrict__ out, float* __restrict__ msum)
{
    __shared__ unsigned short AsL[8192], BsL[8192];
    __shared__ float msS[64];
    const int t = threadIdx.x;
    const int id = blockIdx.x;
    const int b = id & 31, tt = id >> 5;
    const int seg = tt >> 1, nt = tt & 1;
    if (t < 64) msS[t] = 0.f;
    f32x4 acc[2][2];
#pragma unroll
    for (int i = 0; i < 2; i++)
#pragma unroll
        for (int n = 0; n < 2; n++) acc[i][n] = (f32x4){0.f, 0.f, 0.f, 0.f};
    pipe64x64(F1b + ((size_t)b * 512 + seg * 64) * 384, 384,
              WFsT + (size_t)nt * 64 * 384, 384, 6, AsL, BsL, acc, t);

    const int wave = t >> 6, lane = t & 63;
    const int wm = wave >> 1, wn = wave & 1;
    const int quad = lane >> 4, l16 = lane & 15;
    float ls[2];
#pragma unroll
    for (int n = 0; n < 2; n++) ls[n] = 0.f;
#pragma unroll
    for (int i = 0; i < 2; i++) {
        int nd = seg * 64 + wm * 32 + i * 16 + quad * 4;
#pragma unroll
        for (int n = 0; n < 2; n++) {
            int col = nt * 64 + wn * 32 + n * 16 + l16;
            float bb = beffv[col];
#pragma unroll
            for (int r = 0; r < 4; r++) {
                float x = acc[i][n][r] + bb;
                float v = LEAKY(x);
                out[(size_t)b * 65664 + (size_t)(nd + r + 1) * 128 + col] = v;
                ls[n] += v;
            }
        }
    }
#pragma unroll
    for (int n = 0; n < 2; n++) atomicAdd(&msS[wn * 32 + n * 16 + l16], ls[n]);
    __syncthreads();
    if (t < 64) atomicAdd(&msum[b * 128 + nt * 64 + t], msS[t]);
}

// depot row + final means
__global__ void k_meandep(const float* __restrict__ depot, const float* __restrict__ Wd,
                          const float* __restrict__ bd, const float* __restrict__ msum,
                          float* __restrict__ out) {
    int id = blockIdx.x * 256 + threadIdx.x;   // 4096
    int b = id >> 7, o = id & 127;
    float dep = depot[b * 2] * Wd[o] + depot[b * 2 + 1] * Wd[128 + o] + bd[o];
    out[(size_t)b * 65664 + o] = dep;
    out[2101248 + id] = (msum[id] + dep) * (1.0f / 513.0f);
}

// ---------------- launch ----------------

extern "C" void kernel_launch(void* const* d_in, const int* in_sizes, int n_in,
                              void* d_out, int out_size, void* d_ws, size_t ws_size,
                              hipStream_t stream) {
    const float* loc      = (const float*)d_in[0];
    const float* deadline = (const float*)d_in[1];
    const float* depot    = (const float*)d_in[3];
    const float* W_init   = (const float*)d_in[4];
    const float* b_init   = (const float*)d_in[5];
    const float* W_dep    = (const float*)d_in[6];
    const float* b_dep    = (const float*)d_in[7];
    const float* W_g1     = (const float*)d_in[8];
    const float* b_g1     = (const float*)d_in[9];
    const float* W_g2     = (const float*)d_in[10];
    const float* b_g2     = (const float*)d_in[11];
    const float* W_g3     = (const float*)d_in[12];
    const float* b_g3     = (const float*)d_in[13];
    const float* gamma    = (const float*)d_in[14];
    const float* beta     = (const float*)d_in[15];
    const float* W_F      = (const float*)d_in[16];
    const float* b_F      = (const float*)d_in[17];
    float* out = (float*)d_out;
    float* ws  = (float*)d_ws;

    // workspace (float offsets, 16B aligned); ~23.3M floats ~= 93 MB
    float* dmaxv  = ws + 0;         // 4
    float* amaxf  = ws + 4;         // 4
    float* bn1    = ws + 8;         // 384
    float* bn2    = ws + 392;      // 384
    float* msum   = ws + 776;      // 4096
    float* rowsum = ws + 4872;     // 16384
    float* pmax   = ws + 21256;    // 4096
    float* sS     = ws + 25352;    // 384
    float* beffv  = ws + 25736;    // 128
    unsigned short* Lb   = (unsigned short*)(ws + 25864);     // 8388608 u16
    unsigned short* P1   = (unsigned short*)(ws + 4220168);   // 6291456 u16
    unsigned short* P2   = (unsigned short*)(ws + 7365896);
    unsigned short* P3   = (unsigned short*)(ws + 10511624);
    unsigned short* WgT  = (unsigned short*)(ws + 13657352);  // 442368 u16
    unsigned short* WFsT = (unsigned short*)(ws + 13878536);  // 49152 u16
    unsigned short* Y2T  = (unsigned short*)(ws + 13903112);  // 6291456 u16
    unsigned short* ZT   = (unsigned short*)(ws + 17048840);
    unsigned short* F1b  = (unsigned short*)(ws + 20194568);

    hipMemsetAsync(bn1, 0, (384 + 384 + 4096) * sizeof(float), stream);

    k_dmax<<<1, 256, 0, stream>>>(deadline, dmaxv);
    k_rowstats<<<4096, 256, 0, stream>>>(loc, deadline, dmaxv, rowsum, pmax);
    k_amax<<<1, 256, 0, stream>>>(pmax, amaxf);
    k_buildL<<<8192, 256, 0, stream>>>(loc, deadline, dmaxv, rowsum, amaxf, Lb);
    k_F0pow<<<6144, 256, 0, stream>>>(loc, deadline, dmaxv, W_init, b_init, P1, P2, P3);
    k_prepW<<<1728, 256, 0, stream>>>(W_g1, W_g2, W_g3, WgT);

    k_ygemmT<<<768, 256, 0, stream>>>(WgT, P1, P2, P3, Y2T);
    k_lg1T<<<768, 256, 0, stream>>>(Lb, Y2T, WgT, P1, P2, P3, ZT);
    k_lg2<<<768, 256, 0, stream>>>(Lb, ZT, WgT, P1, P2, P3,
                                   b_g1, b_g2, b_g3, F1b, bn1, bn2);

    k_bnfin_beff<<<1, 384, 0, stream>>>(bn1, bn2, gamma, beta, W_F, b_F, sS, beffv);
    k_fold<<<192, 256, 0, stream>>>(W_F, sS, WFsT);
    k_fgemm<<<512, 256, 0, stream>>>(F1b, WFsT, beffv, out, msum);
    k_meandep<<<16, 256, 0, stream>>>(depot, W_dep, b_dep, msum, out);
}

// Round 7
// 239.962 us; speedup vs baseline: 1.0176x; 1.0176x over previous
//
#include <hip/hip_runtime.h>

#define LEAKY(x) ((x) > 0.0f ? (x) : 0.01f * (x))

typedef __attribute__((ext_vector_type(8))) short bf16x8;      // MFMA A/B frag
typedef __attribute__((ext_vector_type(4))) float f32x4;       // MFMA C/D frag
typedef __attribute__((ext_vector_type(8))) unsigned short u16x8;
typedef __attribute__((ext_vector_type(4))) unsigned short u16x4;

__device__ __forceinline__ unsigned short f2bf(float f) {
    unsigned int u = __float_as_uint(f);
    unsigned int r = (u + 0x7fffu + ((u >> 16) & 1u)) >> 16;   // RNE
    return (unsigned short)r;
}
__device__ __forceinline__ float bf2f(unsigned short u) {
    return __uint_as_float(((unsigned int)u) << 16);
}

// Barrier that does NOT drain vmcnt: waits lgkmcnt(0) only (LDS visibility),
// leaves global prefetch loads in flight. imm 0xC07F = vmcnt 63, expcnt 7, lgkmcnt 0.
__device__ __forceinline__ void lds_barrier() {
    __builtin_amdgcn_s_waitcnt(0xC07F);
    __builtin_amdgcn_s_barrier();
}

// ---------------- small builds ----------------

__global__ void k_dmax(const float* __restrict__ deadline, float* __restrict__ dmax) {
    __shared__ float red[256];
    int t = threadIdx.x;
    float m = -1e30f;
    for (int i = t; i < 16384; i += 256) m = fmaxf(m, deadline[i]);
    red[t] = m; __syncthreads();
    for (int s = 128; s > 0; s >>= 1) {
        if (t < s) red[t] = fmaxf(red[t], red[t + s]);
        __syncthreads();
    }
    if (t == 0) *dmax = red[0];
}

// rowsum + per-block max of r=1/dist; R not materialized
__global__ __launch_bounds__(256) void k_rowstats(const float* __restrict__ loc,
                                                  const float* __restrict__ deadline,
                                                  const float* __restrict__ dmaxv,
                                                  float* __restrict__ rowsum, float* __restrict__ pmax) {
    int blk = blockIdx.x;                       // 0..4095
    int wave = threadIdx.x >> 6, lane = threadIdx.x & 63;
    int bi = blk * 4 + wave;                    // b*512 + i
    int b = bi >> 9, i = bi & 511;
    float invd = 1.0f / (*dmaxv);
    const float* lb = loc + b * 1024;
    const float* db = deadline + b * 512;
    float xi = lb[i * 2], yi = lb[i * 2 + 1], zi = db[i] * invd;
    float lsum = 0.f, lmax = 0.f;
    for (int j = lane; j < 512; j += 64) {
        float d0 = xi - lb[j * 2], d1 = yi - lb[j * 2 + 1], d2 = zi - db[j] * invd;
        float dd = d0 * d0 + d1 * d1 + d2 * d2;
        float r = (j == i) ? 0.f : rsqrtf(dd);
        lsum += r; lmax = fmaxf(lmax, r);
    }
    for (int off = 32; off > 0; off >>= 1) {
        lsum += __shfl_down(lsum, off);
        lmax = fmaxf(lmax, __shfl_down(lmax, off));
    }
    __shared__ float smax[4];
    if (lane == 0) { rowsum[bi] = lsum; smax[wave] = lmax; }
    __syncthreads();
    if (threadIdx.x == 0) pmax[blk] = fmaxf(fmaxf(smax[0], smax[1]), fmaxf(smax[2], smax[3]));
}

__global__ void k_amax(const float* __restrict__ pmax, float* __restrict__ amaxf) {
    __shared__ float red[256];
    int t = threadIdx.x;
    float m = 0.f;
    for (int i = t; i < 4096; i += 256) m = fmaxf(m, pmax[i]);
    red[t] = m; __syncthreads();
    for (int s = 128; s > 0; s >>= 1) {
        if (t < s) red[t] = fmaxf(red[t], red[t + s]);
        __syncthreads();
    }
    if (t == 0) *amaxf = red[0];
}

// L bf16 (symmetric), recomputing r on the fly
__global__ void k_buildL(const float* __restrict__ loc, const float* __restrict__ deadline,
                         const float* __restrict__ dmaxv, const float* __restrict__ rowsum,
                         const float* __restrict__ amaxf, unsigned short* __restrict__ Lb) {
    int id = blockIdx.x * 256 + threadIdx.x;     // 2,097,152 threads * 4 elems
    float inv = 1.0f / (*amaxf);
    float invd = 1.0f / (*dmaxv);
    size_t e = (size_t)id * 4;
    size_t bi = e >> 9;
    int b = (int)(bi >> 9);
    int i = (int)(bi & 511);
    int j0 = (int)(e & 511);
    const float* lb = loc + b * 1024;
    const float* db = deadline + b * 512;
    float xi = lb[i * 2], yi = lb[i * 2 + 1], zi = db[i] * invd;
    float4 l01 = *(const float4*)(lb + j0 * 2);
    float4 l23 = *(const float4*)(lb + j0 * 2 + 4);
    float4 dj = *(const float4*)(db + j0);
    float diag = rowsum[bi] * inv - 1.0f;
    float jx[4] = {l01.x, l01.z, l23.x, l23.z};
    float jy[4] = {l01.y, l01.w, l23.y, l23.w};
    float jz[4] = {dj.x * invd, dj.y * invd, dj.z * invd, dj.w * invd};
    u16x4 o;
#pragma unroll
    for (int j = 0; j < 4; j++) {
        float d0 = xi - jx[j], d1 = yi - jy[j], d2 = zi - jz[j];
        float dd = d0 * d0 + d1 * d1 + d2 * d2;
        float v = (i == j0 + j) ? diag : -rsqrtf(dd) * inv;
        o[j] = f2bf(v);
    }
    *(u16x4*)(Lb + e) = o;
}

// F0 powers, bf16 row-major [16384][384] x3, 4 cols per thread
__global__ void k_F0pow(const float* __restrict__ loc, const float* __restrict__ deadline,
                        const float* __restrict__ dmaxv,
                        const float* __restrict__ Wi, const float* __restrict__ bi_,
                        unsigned short* __restrict__ P1, unsigned short* __restrict__ P2,
                        unsigned short* __restrict__ P3) {
    int id = blockIdx.x * 256 + threadIdx.x;     // 1,572,864
    int row = id / 96, c4 = (id % 96) * 4;
    float x0 = loc[row * 2], x1 = loc[row * 2 + 1], x2 = deadline[row] / (*dmaxv);
    float4 w0 = *(const float4*)(Wi + c4);
    float4 w1 = *(const float4*)(Wi + 384 + c4);
    float4 w2 = *(const float4*)(Wi + 768 + c4);
    float4 bb = *(const float4*)(bi_ + c4);
    float f[4] = {x0 * w0.x + x1 * w1.x + x2 * w2.x + bb.x,
                  x0 * w0.y + x1 * w1.y + x2 * w2.y + bb.y,
                  x0 * w0.z + x1 * w1.z + x2 * w2.z + bb.z,
                  x0 * w0.w + x1 * w1.w + x2 * w2.w + bb.w};
    u16x4 o1, o2, o3;
#pragma unroll
    for (int j = 0; j < 4; j++) {
        o1[j] = f2bf(f[j]); o2[j] = f2bf(f[j] * f[j]); o3[j] = f2bf(f[j] * f[j] * f[j]);
    }
    size_t e = (size_t)row * 384 + c4;
    *(u16x4*)(P1 + e) = o1; *(u16x4*)(P2 + e) = o2; *(u16x4*)(P3 + e) = o3;
}

// WgT[combo][n][k] = Wg{kp}[(part*384+k)*128 + n]
__global__ void k_prepW(const float* __restrict__ Wg1, const float* __restrict__ Wg2,
                        const float* __restrict__ Wg3, unsigned short* __restrict__ WgT) {
    int id = blockIdx.x * 256 + threadIdx.x;     // 442368 exact
    int combo = id / 49152, rem = id % 49152;
    int n = rem / 384, k = rem % 384;
    int kp = combo / 3, part = combo % 3;
    const float* W = (kp == 0) ? Wg1 : (kp == 1 ? Wg2 : Wg3);
    WgT[id] = f2bf(W[(part * 384 + k) * 128 + n]);
}

// ---------------- pipelined MFMA cores ----------------
// Depth-2 register prefetch + double-buffered LDS, ONE lds_barrier per iter (BK=64).
// lds_barrier keeps global prefetch loads in flight across the barrier (no vmcnt drain).
// LDS rows of 64 u16 = 8 chunks of 16B; chunk XOR-swizzled by (row&7).
// 128x64 tile: 4 waves 2x2, wave tile 64x32 (4x2 frags), 16 MFMA/wave/iter.

__device__ __forceinline__ void pipe128x64(
    const unsigned short* __restrict__ A0, int As0, const unsigned short* __restrict__ B0, int Bs0, int it0,
    const unsigned short* __restrict__ A1, int As1, const unsigned short* __restrict__ B1, int Bs1, int it1,
    unsigned short* AsL, unsigned short* BsL,   // 16384 / 8192 u16 (double-buffered)
    f32x4 (&acc)[4][2], int t)
{
    const int lane = t & 63, wave = t >> 6;
    const int wm = wave >> 1, wn = wave & 1;
    const int quad = lane >> 4, l16 = lane & 15;
    const int ra = t >> 1, ca = (t & 1) * 4;        // A: 128 rows, 4 chunks/thread
    const int rb = t >> 2, cb = (t & 3) * 2;        // B: 64 rows, 2 chunks/thread
    const unsigned short* Ar0 = A0 + (size_t)ra * As0;
    const unsigned short* Ar1 = A1 ? (A1 + (size_t)ra * As1) : Ar0;
    const unsigned short* Br0 = B0 + (size_t)rb * Bs0;
    const unsigned short* Br1 = B1 ? (B1 + (size_t)rb * Bs1) : Br0;
    const int total = it0 + it1;                     // even in all call sites

    u16x8 paA[4], pbA[2], paB[4], pbB[2];

    auto loadStage = [&](int idx, u16x8 (&pa)[4], u16x8 (&pb)[2]) {
        int sg = (idx >= it0);
        int k0 = (sg ? idx - it0 : idx) * 64;
        const unsigned short* Ar = sg ? Ar1 : Ar0;
        const unsigned short* Br = sg ? Br1 : Br0;
#pragma unroll
        for (int j = 0; j < 4; j++) pa[j] = *(const u16x8*)(Ar + k0 + (ca + j) * 8);
#pragma unroll
        for (int j = 0; j < 2; j++) pb[j] = *(const u16x8*)(Br + k0 + (cb + j) * 8);
    };
    auto writeStage = [&](int bf_, u16x8 (&pa)[4], u16x8 (&pb)[2]) {
#pragma unroll
        for (int j = 0; j < 4; j++)
            *(u16x8*)(AsL + bf_ * 8192 + ra * 64 + (((ca + j) ^ (ra & 7)) * 8)) = pa[j];
#pragma unroll
        for (int j = 0; j < 2; j++)
            *(u16x8*)(BsL + bf_ * 4096 + rb * 64 + (((cb + j) ^ (rb & 7)) * 8)) = pb[j];
    };
    auto mfmaStep = [&](int bf_) {
#pragma unroll
        for (int h = 0; h < 2; h++) {
            bf16x8 af[4], bfr[2];
            int phys = ((h * 4 + quad) ^ (l16 & 7)) * 8;
#pragma unroll
            for (int i = 0; i < 4; i++)
                af[i] = *(const bf16x8*)(AsL + bf_ * 8192 + (wm * 64 + i * 16 + l16) * 64 + phys);
#pragma unroll
            for (int n = 0; n < 2; n++)
                bfr[n] = *(const bf16x8*)(BsL + bf_ * 4096 + (wn * 32 + n * 16 + l16) * 64 + phys);
#pragma unroll
            for (int i = 0; i < 4; i++)
#pragma unroll
                for (int n = 0; n < 2; n++)
                    acc[i][n] = __builtin_amdgcn_mfma_f32_16x16x32_bf16(af[i], bfr[n], acc[i][n], 0, 0, 0);
        }
    };

    loadStage(0, paA, pbA);
    loadStage(1, paB, pbB);

    int buf = 0;
    for (int s = 0; s < total; s += 2) {
        writeStage(buf, paA, pbA);
        lds_barrier();
        if (s + 2 < total) loadStage(s + 2, paA, pbA);
        mfmaStep(buf);
        buf ^= 1;

        writeStage(buf, paB, pbB);
        lds_barrier();
        if (s + 3 < total) loadStage(s + 3, paB, pbB);
        mfmaStep(buf);
        buf ^= 1;
    }
}

// 64x64 tile: wave tile 32x32 (2x2 frags), 8 MFMA/wave/iter, depth-2 prefetch
__device__ __forceinline__ void pipe64x64(
    const unsigned short* __restrict__ A0, int As0, const unsigned short* __restrict__ B0, int Bs0, int it0,
    unsigned short* AsL, unsigned short* BsL,   // 8192 / 8192 u16
    f32x4 (&acc)[2][2], int t)
{
    const int lane = t & 63, wave = t >> 6;
    const int wm = wave >> 1, wn = wave & 1;
    const int quad = lane >> 4, l16 = lane & 15;
    const int rb = t >> 2, cb = (t & 3) * 2;
    const unsigned short* Ar0 = A0 + (size_t)rb * As0;
    const unsigned short* Br0 = B0 + (size_t)rb * Bs0;

    u16x8 paA[2], pbA[2], paB[2], pbB[2];
    auto loadStage = [&](int idx, u16x8 (&pa)[2], u16x8 (&pb)[2]) {
        int k0 = idx * 64;
#pragma unroll
        for (int j = 0; j < 2; j++) { pa[j] = *(const u16x8*)(Ar0 + k0 + (cb + j) * 8);
                                      pb[j] = *(const u16x8*)(Br0 + k0 + (cb + j) * 8); }
    };
    auto writeStage = [&](int bf_, u16x8 (&pa)[2], u16x8 (&pb)[2]) {
#pragma unroll
        for (int j = 0; j < 2; j++) {
            int phys = ((cb + j) ^ (rb & 7)) * 8;
            *(u16x8*)(AsL + bf_ * 4096 + rb * 64 + phys) = pa[j];
            *(u16x8*)(BsL + bf_ * 4096 + rb * 64 + phys) = pb[j];
        }
    };
    auto mfmaStep = [&](int bf_) {
#pragma unroll
        for (int h = 0; h < 2; h++) {
            bf16x8 af[2], bfr[2];
            int phys = ((h * 4 + quad) ^ (l16 & 7)) * 8;
#pragma unroll
            for (int i = 0; i < 2; i++)
                af[i] = *(const bf16x8*)(AsL + bf_ * 4096 + (wm * 32 + i * 16 + l16) * 64 + phys);
#pragma unroll
            for (int n = 0; n < 2; n++)
                bfr[n] = *(const bf16x8*)(BsL + bf_ * 4096 + (wn * 32 + n * 16 + l16) * 64 + phys);
#pragma unroll
            for (int i = 0; i < 2; i++)
#pragma unroll
                for (int n = 0; n < 2; n++)
                    acc[i][n] = __builtin_amdgcn_mfma_f32_16x16x32_bf16(af[i], bfr[n], acc[i][n], 0, 0, 0);
        }
    };

    loadStage(0, paA, pbA);
    loadStage(1, paB, pbB);
    int buf = 0;
    for (int s = 0; s < it0; s += 2) {
        writeStage(buf, paA, pbA);
        lds_barrier();
        if (s + 2 < it0) loadStage(s + 2, paA, pbA);
        mfmaStep(buf);
        buf ^= 1;
        writeStage(buf, paB, pbB);
        lds_barrier();
        if (s + 3 < it0) loadStage(s + 3, paB, pbB);
        mfmaStep(buf);
        buf ^= 1;
    }
}

// Y2^T ; grid 768, id = b + 32*(kp + 3*nb)  (batch->XCD pinned, kp fastest)
__global__ __launch_bounds__(256) void k_ygemmT(
    const unsigned short* __restrict__ WgT,
    const unsigned short* __restrict__ P1, const unsigned short* __restrict__ P2,
    const unsigned short* __restrict__ P3, unsigned short* __restrict__ Y2T)
{
    __shared__ unsigned short AsL[16384], BsL[8192];
    const int t = threadIdx.x;
    const int id = blockIdx.x;
    const int b = id & 31, tt = id >> 5;
    const int kp = tt % 3, nb = tt / 3;
    const unsigned short* P = (kp == 0) ? P1 : (kp == 1 ? P2 : P3);
    f32x4 acc[4][2];
#pragma unroll
    for (int i = 0; i < 4; i++)
#pragma unroll
        for (int n = 0; n < 2; n++) acc[i][n] = (f32x4){0.f, 0.f, 0.f, 0.f};
    pipe128x64(WgT + (size_t)(kp * 3 + 2) * 49152, 384,
               P + ((size_t)b * 512 + nb * 64) * 384, 384, 6,
               nullptr, 0, nullptr, 0, 0, AsL, BsL, acc, t);

    const int wave = t >> 6, lane = t & 63;
    const int wm = wave >> 1, wn = wave & 1;
    const int quad = lane >> 4, l16 = lane & 15;
#pragma unroll
    for (int i = 0; i < 4; i++)
#pragma unroll
        for (int n = 0; n < 2; n++) {
            int g = kp * 128 + wm * 64 + i * 16 + quad * 4;
            int node = nb * 64 + wn * 32 + n * 16 + l16;
#pragma unroll
            for (int r = 0; r < 4; r++)
                Y2T[((size_t)b * 384 + g + r) * 512 + node] = f2bf(acc[i][n][r]);
        }
}

// Z^T = Y2T·L + WgT(part1)·P ; grid 768, id = b + 32*(kp + 3*nb)
__global__ __launch_bounds__(256) void k_lg1T(
    const unsigned short* __restrict__ Lb, const unsigned short* __restrict__ Y2T,
    const unsigned short* __restrict__ WgT,
    const unsigned short* __restrict__ P1, const unsigned short* __restrict__ P2,
    const unsigned short* __restrict__ P3, unsigned short* __restrict__ ZT)
{
    __shared__ unsigned short AsL[16384], BsL[8192];
    const int t = threadIdx.x;
    const int id = blockIdx.x;
    const int b = id & 31, tt = id >> 5;
    const int kp = tt % 3, nb = tt / 3;
    const unsigned short* P = (kp == 0) ? P1 : (kp == 1 ? P2 : P3);
    f32x4 acc[4][2];
#pragma unroll
    for (int i = 0; i < 4; i++)
#pragma unroll
        for (int n = 0; n < 2; n++) acc[i][n] = (f32x4){0.f, 0.f, 0.f, 0.f};
    pipe128x64(Y2T + (size_t)b * 196608 + (size_t)kp * 128 * 512, 512,
               Lb + (size_t)b * 262144 + (size_t)nb * 64 * 512, 512, 8,
               WgT + (size_t)(kp * 3 + 1) * 49152, 384,
               P + ((size_t)b * 512 + nb * 64) * 384, 384, 6, AsL, BsL, acc, t);

    const int wave = t >> 6, lane = t & 63;
    const int wm = wave >> 1, wn = wave & 1;
    const int quad = lane >> 4, l16 = lane & 15;
#pragma unroll
    for (int i = 0; i < 4; i++)
#pragma unroll
        for (int n = 0; n < 2; n++) {
            int g = kp * 128 + wm * 64 + i * 16 + quad * 4;
            int node = nb * 64 + wn * 32 + n * 16 + l16;
#pragma unroll
            for (int r = 0; r < 4; r++)
                ZT[((size_t)b * 384 + g + r) * 512 + node] = f2bf(acc[i][n][r]);
        }
}

// F1 = leaky(L·ZT + P·WgT(part0) + bias) + F0 ; fused BN sums
// grid 768, id = b + 32*(gt + 6*mb)  (gt fastest)
__global__ __launch_bounds__(256) void k_lg2(
    const unsigned short* __restrict__ Lb, const unsigned short* __restrict__ ZT,
    const unsigned short* __restrict__ WgT,
    const unsigned short* __restrict__ P1, const unsigned short* __restrict__ P2,
    const unsigned short* __restrict__ P3,
    const float* __restrict__ bg1, const float* __restrict__ bg2, const float* __restrict__ bg3,
    unsigned short* __restrict__ F1b, float* __restrict__ bn1, float* __restrict__ bn2)
{
    __shared__ unsigned short AsL[16384], BsL[8192];
    __shared__ float bnS[64], bnQ[64];
    const int t = threadIdx.x;
    const int id = blockIdx.x;
    const int b = id & 31, tt = id >> 5;
    const int gt = tt % 6, mb = tt / 6;          // mb: node tile(128), gt: gcol tile(64)
    const int kp = gt >> 1;
    if (t < 64) { bnS[t] = 0.f; bnQ[t] = 0.f; }
    const unsigned short* P = (kp == 0) ? P1 : (kp == 1 ? P2 : P3);
    f32x4 acc[4][2];
#pragma unroll
    for (int i = 0; i < 4; i++)
#pragma unroll
        for (int n = 0; n < 2; n++) acc[i][n] = (f32x4){0.f, 0.f, 0.f, 0.f};
    pipe128x64(Lb + (size_t)b * 262144 + (size_t)mb * 128 * 512, 512,
               ZT + (size_t)b * 196608 + (size_t)gt * 64 * 512, 512, 8,
               P + ((size_t)b * 512 + mb * 128) * 384, 384,
               WgT + (size_t)(kp * 3) * 49152 + (size_t)(gt & 1) * 64 * 384, 384, 6,
               AsL, BsL, acc, t);

    const int wave = t >> 6, lane = t & 63;
    const int wm = wave >> 1, wn = wave & 1;
    const int quad = lane >> 4, l16 = lane & 15;
    const float* bg = (kp == 0) ? bg1 : (kp == 1 ? bg2 : bg3);
    float ls1[2], ls2[2];
#pragma unroll
    for (int n = 0; n < 2; n++) { ls1[n] = 0.f; ls2[n] = 0.f; }
#pragma unroll
    for (int i = 0; i < 4; i++) {
        int rowl = mb * 128 + wm * 64 + i * 16 + quad * 4;
        size_t rowg = (size_t)b * 512 + rowl;
#pragma unroll
        for (int n = 0; n < 2; n++) {
            int nloc = wn * 32 + n * 16 + l16;
            int g = gt * 64 + nloc;
            float bias = bg[(gt & 1) * 64 + nloc];
#pragma unroll
            for (int r = 0; r < 4; r++) {
                size_t idx = (rowg + r) * 384 + g;
                float c = acc[i][n][r] + bias;
                float v = LEAKY(c) + bf2f(P1[idx]);   // residual +F0
                F1b[idx] = f2bf(v);
                ls1[n] += v; ls2[n] += v * v;
            }
        }
    }
#pragma unroll
    for (int n = 0; n < 2; n++) {
        int nloc = wn * 32 + n * 16 + l16;
        atomicAdd(&bnS[nloc], ls1[n]);
        atomicAdd(&bnQ[nloc], ls2[n]);
    }
    __syncthreads();
    if (t < 64) {
        atomicAdd(&bn1[gt * 64 + t], bnS[t]);
        atomicAdd(&bn2[gt * 64 + t], bnQ[t]);
    }
}

// BN finish + effective bias
__global__ __launch_bounds__(384) void k_bnfin_beff(
    const float* __restrict__ bn1, const float* __restrict__ bn2,
    const float* __restrict__ gamma, const float* __restrict__ beta,
    const float* __restrict__ WF, const float* __restrict__ bF,
    float* __restrict__ sS, float* __restrict__ beffv)
{
    __shared__ float ttL[384];
    int c = threadIdx.x;
    float mu = bn1[c] * (1.f / 16384.f);
    float var = bn2[c] * (1.f / 16384.f) - mu * mu;
    float sc = gamma[c] / sqrtf(var + 1e-5f);
    sS[c] = sc;
    ttL[c] = beta[c] - mu * sc;
    __syncthreads();
    if (c < 128) {
        float a = bF[c];
        for (int k = 0; k < 384; k++) a += ttL[k] * WF[k * 128 + c];
        beffv[c] = a;
    }
}

// WFsT[n][k] = W_F[k][n] * sS[k]
__global__ void k_fold(const float* __restrict__ WF, const float* __restrict__ sS,
                       unsigned short* __restrict__ WFsT) {
    int id = blockIdx.x * 256 + threadIdx.x;   // 49152
    int n = id / 384, k = id % 384;
    WFsT[id] = f2bf(WF[k * 128 + n] * sS[k]);
}

// out rows 1..512 = leaky(F1b @ WFsT + beff); fused column-sum partials
__global__ __launch_bounds__(256) void k_fgemm(
    const unsigned short* __restrict__ F1b, const unsigned short* __restrict__ WFsT,
    const float* __restrict__ beffv, float* __restrict__ out, float* __restrict__ msum)
{
    __shared__ unsigned short AsL[8192], BsL[8192];
    __shared__ float msS[64];
    const int t = threadIdx.x;
    const int id = blockIdx.x;
    const int b = id & 31, tt = id >> 5;
    const int seg = tt >> 1, nt = tt & 1;
    if (t < 64) msS[t] = 0.f;
    f32x4 acc[2][2];
#pragma unroll
    for (int i = 0; i < 2; i++)
#pragma unroll
        for (int n = 0; n < 2; n++) acc[i][n] = (f32x4){0.f, 0.f, 0.f, 0.f};
    pipe64x64(F1b + ((size_t)b * 512 + seg * 64) * 384, 384,
              WFsT + (size_t)nt * 64 * 384, 384, 6, AsL, BsL, acc, t);

    const int wave = t >> 6, lane = t & 63;
    const int wm = wave >> 1, wn = wave & 1;
    const int quad = lane >> 4, l16 = lane & 15;
    float ls[2];
#pragma unroll
    for (int n = 0; n < 2; n++) ls[n] = 0.f;
#pragma unroll
    for (int i = 0; i < 2; i++) {
        int nd = seg * 64 + wm * 32 + i * 16 + quad * 4;
#pragma unroll
        for (int n = 0; n < 2; n++) {
            int col = nt * 64 + wn * 32 + n * 16 + l16;
            float bb = beffv[col];
#pragma unroll
            for (int r = 0; r < 4; r++) {
                float x = acc[i][n][r] + bb;
                float v = LEAKY(x);
                out[(size_t)b * 65664 + (size_t)(nd + r + 1) * 128 + col] = v;
                ls[n] += v;
            }
        }
    }
#pragma unroll
    for (int n = 0; n < 2; n++) atomicAdd(&msS[wn * 32 + n * 16 + l16], ls[n]);
    __syncthreads();
    if (t < 64) atomicAdd(&msum[b * 128 + nt * 64 + t], msS[t]);
}

// depot row + final means
__global__ void k_meandep(const float* __restrict__ depot, const float* __restrict__ Wd,
                          const float* __restrict__ bd, const float* __restrict__ msum,
                          float* __restrict__ out) {
    int id = blockIdx.x * 256 + threadIdx.x;   // 4096
    int b = id >> 7, o = id & 127;
    float dep = depot[b * 2] * Wd[o] + depot[b * 2 + 1] * Wd[128 + o] + bd[o];
    out[(size_t)b * 65664 + o] = dep;
    out[2101248 + id] = (msum[id] + dep) * (1.0f / 513.0f);
}

// ---------------- launch ----------------

extern "C" void kernel_launch(void* const* d_in, const int* in_sizes, int n_in,
                              void* d_out, int out_size, void* d_ws, size_t ws_size,
                              hipStream_t stream) {
    const float* loc      = (const float*)d_in[0];
    const float* deadline = (const float*)d_in[1];
    const float* depot    = (const float*)d_in[3];
    const float* W_init   = (const float*)d_in[4];
    const float* b_init   = (const float*)d_in[5];
    const float* W_dep    = (const float*)d_in[6];
    const float* b_dep    = (const float*)d_in[7];
    const float* W_g1     = (const float*)d_in[8];
    const float* b_g1     = (const float*)d_in[9];
    const float* W_g2     = (const float*)d_in[10];
    const float* b_g2     = (const float*)d_in[11];
    const float* W_g3     = (const float*)d_in[12];
    const float* b_g3     = (const float*)d_in[13];
    const float* gamma    = (const float*)d_in[14];
    const float* beta     = (const float*)d_in[15];
    const float* W_F      = (const float*)d_in[16];
    const float* b_F      = (const float*)d_in[17];
    float* out = (float*)d_out;
    float* ws  = (float*)d_ws;

    // workspace (float offsets, 16B aligned); ~23.3M floats ~= 93 MB
    float* dmaxv  = ws + 0;         // 4
    float* amaxf  = ws + 4;         // 4
    float* bn1    = ws + 8;         // 384
    float* bn2    = ws + 392;      // 384
    float* msum   = ws + 776;      // 4096
    float* rowsum = ws + 4872;     // 16384
    float* pmax   = ws + 21256;    // 4096
    float* sS     = ws + 25352;    // 384
    float* beffv  = ws + 25736;    // 128
    unsigned short* Lb   = (unsigned short*)(ws + 25864);     // 8388608 u16
    unsigned short* P1   = (unsigned short*)(ws + 4220168);   // 6291456 u16
    unsigned short* P2   = (unsigned short*)(ws + 7365896);
    unsigned short* P3   = (unsigned short*)(ws + 10511624);
    unsigned short* WgT  = (unsigned short*)(ws + 13657352);  // 442368 u16
    unsigned short* WFsT = (unsigned short*)(ws + 13878536);  // 49152 u16
    unsigned short* Y2T  = (unsigned short*)(ws + 13903112);  // 6291456 u16
    unsigned short* ZT   = (unsigned short*)(ws + 17048840);
    unsigned short* F1b  = (unsigned short*)(ws + 20194568);

    hipMemsetAsync(bn1, 0, (384 + 384 + 4096) * sizeof(float), stream);

    k_dmax<<<1, 256, 0, stream>>>(deadline, dmaxv);
    k_rowstats<<<4096, 256, 0, stream>>>(loc, deadline, dmaxv, rowsum, pmax);
    k_amax<<<1, 256, 0, stream>>>(pmax, amaxf);
    k_buildL<<<8192, 256, 0, stream>>>(loc, deadline, dmaxv, rowsum, amaxf, Lb);
    k_F0pow<<<6144, 256, 0, stream>>>(loc, deadline, dmaxv, W_init, b_init, P1, P2, P3);
    k_prepW<<<1728, 256, 0, stream>>>(W_g1, W_g2, W_g3, WgT);

    k_ygemmT<<<768, 256, 0, stream>>>(WgT, P1, P2, P3, Y2T);
    k_lg1T<<<768, 256, 0, stream>>>(Lb, Y2T, WgT, P1, P2, P3, ZT);
    k_lg2<<<768, 256, 0, stream>>>(Lb, ZT, WgT, P1, P2, P3,
                                   b_g1, b_g2, b_g3, F1b, bn1, bn2);

    k_bnfin_beff<<<1, 384, 0, stream>>>(bn1, bn2, gamma, beta, W_F, b_F, sS, beffv);
    k_fold<<<192, 256, 0, stream>>>(W_F, sS, WFsT);
    k_fgemm<<<512, 256, 0, stream>>>(F1b, WFsT, beffv, out, msum);
    k_meandep<<<16, 256, 0, stream>>>(depot, W_dep, b_dep, msum, out);
}